// Round 1
// baseline (106.564 us; speedup 1.0000x reference)
//
#include <hip/hip_runtime.h>
#include <hip/hip_bf16.h>

#define N_CODECS 1024
#define EPS 1e-8f

// ---------------------------------------------------------------------------
// Kernel 1: zero the global bin array (d_ws is poisoned 0xAA before each call)
// ---------------------------------------------------------------------------
__global__ void zero_bins_kernel(unsigned int* __restrict__ gcounts) {
    int i = blockIdx.x * blockDim.x + threadIdx.x;
    if (i < N_CODECS) gcounts[i] = 0u;
}

// ---------------------------------------------------------------------------
// Kernel 2: LDS-privatized histogram.
// Each block keeps a private 1024-bin histogram in LDS (4 KB), walks the
// input with int4 (16 B) vectorized grid-stride loads, then merges to the
// global bin array with one atomicAdd per bin.
// ---------------------------------------------------------------------------
__global__ void __launch_bounds__(256) hist_kernel(
        const int* __restrict__ idx,
        unsigned int* __restrict__ gcounts,
        int n4 /* number of int4 elements */) {
    __shared__ unsigned int lcounts[N_CODECS];
    for (int i = threadIdx.x; i < N_CODECS; i += blockDim.x) lcounts[i] = 0u;
    __syncthreads();

    const int4* __restrict__ idx4 = (const int4*)idx;
    int stride = gridDim.x * blockDim.x;
    for (int i = blockIdx.x * blockDim.x + threadIdx.x; i < n4; i += stride) {
        int4 v = idx4[i];
        atomicAdd(&lcounts[v.x], 1u);
        atomicAdd(&lcounts[v.y], 1u);
        atomicAdd(&lcounts[v.z], 1u);
        atomicAdd(&lcounts[v.w], 1u);
    }
    __syncthreads();

    for (int i = threadIdx.x; i < N_CODECS; i += blockDim.x) {
        unsigned int c = lcounts[i];
        if (c) atomicAdd(&gcounts[i], c);
    }
}

// ---------------------------------------------------------------------------
// Kernel 3: finalize. 1 block x 1024 threads: p = count/N, term = p*log(p+eps),
// block reduction (wave shuffle + LDS across 16 waves), out = exp(-sum).
// ---------------------------------------------------------------------------
__global__ void __launch_bounds__(1024) finalize_kernel(
        const unsigned int* __restrict__ gcounts,
        float* __restrict__ out,
        float invN) {
    int t = threadIdx.x;
    float p = (float)gcounts[t] * invN;
    float term = p * logf(p + EPS);

    // wave-64 shuffle reduction
    #pragma unroll
    for (int off = 32; off > 0; off >>= 1) {
        term += __shfl_down(term, off, 64);
    }

    __shared__ float wsum[16];
    int wave = t >> 6;
    int lane = t & 63;
    if (lane == 0) wsum[wave] = term;
    __syncthreads();

    if (wave == 0) {
        float s = (lane < 16) ? wsum[lane] : 0.0f;
        #pragma unroll
        for (int off = 8; off > 0; off >>= 1) {
            s += __shfl_down(s, off, 64);
        }
        if (lane == 0) out[0] = expf(-s);
    }
}

extern "C" void kernel_launch(void* const* d_in, const int* in_sizes, int n_in,
                              void* d_out, int out_size, void* d_ws, size_t ws_size,
                              hipStream_t stream) {
    const int* indices = (const int*)d_in[0];
    int n = in_sizes[0];             // 16 * 1048576 = 16,777,216
    float* out = (float*)d_out;
    unsigned int* gcounts = (unsigned int*)d_ws;  // 1024 * 4 B = 4 KB scratch

    int n4 = n >> 2;                 // divisible by 4

    // 1) zero bins
    zero_bins_kernel<<<(N_CODECS + 255) / 256, 256, 0, stream>>>(gcounts);

    // 2) histogram: 1024 blocks x 256 threads, each thread does 16 int4 loads
    hist_kernel<<<1024, 256, 0, stream>>>(indices, gcounts, n4);

    // 3) entropy + perplexity
    finalize_kernel<<<1, 1024, 0, stream>>>(gcounts, out, 1.0f / (float)n);
}

// Round 2
// 94.064 us; speedup vs baseline: 1.1329x; 1.1329x over previous
//
#include <hip/hip_runtime.h>
#include <hip/hip_bf16.h>

#define N_CODECS 1024
#define EPS 1e-8f
#define HIST_BLOCKS 1024
#define CHUNKS 16              // 1024 partials reduced in 16 chunks of 64

// ---------------------------------------------------------------------------
// Kernel 1: per-block LDS histogram -> private partial in d_ws (NO global
// atomics, no init kernel needed: every bin of every partial is plain-stored).
// ---------------------------------------------------------------------------
__global__ void __launch_bounds__(256) hist_partial_kernel(
        const int* __restrict__ idx,
        unsigned int* __restrict__ gpart,   // [HIST_BLOCKS][N_CODECS]
        int n4) {
    __shared__ unsigned int lcounts[N_CODECS];
    for (int i = threadIdx.x; i < N_CODECS; i += 256) lcounts[i] = 0u;
    __syncthreads();

    const int4* __restrict__ idx4 = (const int4*)idx;
    int stride = gridDim.x * 256;
    for (int i = blockIdx.x * 256 + threadIdx.x; i < n4; i += stride) {
        int4 v = idx4[i];
        atomicAdd(&lcounts[v.x], 1u);   // LDS atomics only
        atomicAdd(&lcounts[v.y], 1u);
        atomicAdd(&lcounts[v.z], 1u);
        atomicAdd(&lcounts[v.w], 1u);
    }
    __syncthreads();

    // contention-free merge: plain coalesced stores to this block's slice
    unsigned int* __restrict__ mypart = gpart + (size_t)blockIdx.x * N_CODECS;
    #pragma unroll
    for (int i = 0; i < N_CODECS / 256; ++i) {
        int b = i * 256 + threadIdx.x;
        mypart[b] = lcounts[b];
    }
}

// ---------------------------------------------------------------------------
// Kernel 2: reduce 1024 partials -> 16 chunk partials (column sums).
// Grid: 64 blocks x 256 threads. Block (c,q): chunk c=blk>>2, quarter q=blk&3.
// Thread handles bin = q*256 + tid, sums 64 partials. Fully coalesced.
// ---------------------------------------------------------------------------
__global__ void __launch_bounds__(256) reduce_kernel(
        const unsigned int* __restrict__ gpart,   // [HIST_BLOCKS][N_CODECS]
        unsigned int* __restrict__ p2) {          // [CHUNKS][N_CODECS]
    int c = blockIdx.x >> 2;
    int q = blockIdx.x & 3;
    int bin = q * 256 + threadIdx.x;

    const unsigned int* __restrict__ base = gpart + (size_t)(c * 64) * N_CODECS + bin;
    unsigned int s0 = 0, s1 = 0, s2 = 0, s3 = 0;
    #pragma unroll 4
    for (int k = 0; k < 64; k += 4) {
        s0 += base[(size_t)(k + 0) * N_CODECS];
        s1 += base[(size_t)(k + 1) * N_CODECS];
        s2 += base[(size_t)(k + 2) * N_CODECS];
        s3 += base[(size_t)(k + 3) * N_CODECS];
    }
    p2[c * N_CODECS + bin] = s0 + s1 + s2 + s3;
}

// ---------------------------------------------------------------------------
// Kernel 3: finalize. 1 block x 1024 threads: sum 16 chunk values per bin,
// p = count/N, term = p*log(p+eps), block reduce, out = exp(-sum).
// ---------------------------------------------------------------------------
__global__ void __launch_bounds__(1024) finalize_kernel(
        const unsigned int* __restrict__ p2,      // [CHUNKS][N_CODECS]
        float* __restrict__ out,
        float invN) {
    int t = threadIdx.x;
    unsigned int cnt = 0;
    #pragma unroll
    for (int c = 0; c < CHUNKS; ++c) cnt += p2[c * N_CODECS + t];

    float p = (float)cnt * invN;
    float term = p * logf(p + EPS);

    #pragma unroll
    for (int off = 32; off > 0; off >>= 1) term += __shfl_down(term, off, 64);

    __shared__ float wsum[16];
    int wave = t >> 6;
    int lane = t & 63;
    if (lane == 0) wsum[wave] = term;
    __syncthreads();

    if (wave == 0) {
        float s = (lane < 16) ? wsum[lane] : 0.0f;
        #pragma unroll
        for (int off = 8; off > 0; off >>= 1) s += __shfl_down(s, off, 64);
        if (lane == 0) out[0] = expf(-s);
    }
}

extern "C" void kernel_launch(void* const* d_in, const int* in_sizes, int n_in,
                              void* d_out, int out_size, void* d_ws, size_t ws_size,
                              hipStream_t stream) {
    const int* indices = (const int*)d_in[0];
    int n = in_sizes[0];             // 16 * 1048576 = 16,777,216
    float* out = (float*)d_out;

    unsigned int* gpart = (unsigned int*)d_ws;                       // 4 MB
    unsigned int* p2    = gpart + (size_t)HIST_BLOCKS * N_CODECS;    // 64 KB

    int n4 = n >> 2;

    hist_partial_kernel<<<HIST_BLOCKS, 256, 0, stream>>>(indices, gpart, n4);
    reduce_kernel<<<CHUNKS * 4, 256, 0, stream>>>(gpart, p2);
    finalize_kernel<<<1, 1024, 0, stream>>>(p2, out, 1.0f / (float)n);
}